// Round 6
// baseline (770.275 us; speedup 1.0000x reference)
//
#include <hip/hip_runtime.h>
#include <stdint.h>

// Fused attention: S=(x1@x2^T)*0.2; P=softmax(S); P=mask?P/0.9:0; O=P@x3
// B=16, SQ=SK=2048, D=DV=128. fp32 in/out, int32 mask, bf16 MFMA compute.
//
// R9 vs R8 (418.7us total, main ~124us; counted-vmcnt was NEUTRAL => barrier
// drain not the cost. LDS pipe ~2900cyc/tile/CU (62% of wall) + lockstep):
//  1. K/V IN REGISTERS, loaded per-wave directly from the swizzled Kz/Vz
//     global layouts (L2-resident) with global_load_dwordx4 — byte-identical
//     fragments to the old LDS path. V issued at tile start (L2 ~200cy,
//     consumed after QK^T+softmax); K ping-ponged one tile ahead; masks one
//     tile ahead, bit-packed 16->1 reg at consume to cap live VGPRs.
//  2. BARRIER-FREE main loop: no __shared__ K/V staging at all -> zero
//     __syncthreads in the tile loop. Waves slip freely; all waits are
//     precise per-register vmcnt. LDS keeps only wave-private Ps transpose
//     (16 ds_write_b16 + 2 ds_read_b128 per tile): ~2900 -> ~600 cyc/tile/CU.
//  3. LDS = union{Ps 10KB | epilogue oxch 33KB} -> 33KB/block; VGPR ~240
//     capped by __launch_bounds__(256,2) -> 2 blocks/CU as before.
//  Carried: 64q x 64k block / 4 waves (32q x 32k); prep_k/prep_v bf16+XOR
//  pre-passes; XCD-chunked swizzle; exp2 softmax (static-max); cvt_pk;
//  setprio around MFMA; cross-wk epilogue combine.
//  Fallback (ws < 16MB): R4 kernel.

#define B_   16
#define SQ_  2048
#define SK_  2048
#define D_   128
#define DV_  128
#define BK   64
#define NT   (SK_ / BK)   // 32 tiles

typedef short  s16x8 __attribute__((ext_vector_type(8)));   // MFMA A/B frag
typedef float  f32x4 __attribute__((ext_vector_type(4)));   // MFMA C/D frag
typedef unsigned int u32x4 __attribute__((ext_vector_type(4)));
typedef unsigned short u16;
typedef unsigned int   u32;

// f32 pair -> packed bf16x2, RNE, single instruction (no builtin on gfx950).
__device__ __forceinline__ u32 pk2(float a, float b) {
    u32 r;
    asm("v_cvt_pk_bf16_f32 %0, %1, %2" : "=v"(r) : "v"(a), "v"(b));
    return r;
}
__device__ __forceinline__ u16 f2bf(float f) { return (u16)pk2(f, 0.0f); }

// ---------------- pre-pass: K -> bf16, bank-swizzled ----------------
// Kz[b][k][c] with c = col ^ ((k&7)<<3). 8 MB.
__global__ __launch_bounds__(256)
void prep_k(const float* __restrict__ Kg, u16* __restrict__ Kz)
{
    int g   = blockIdx.x * 256 + threadIdx.x;   // 524288 = 16*2048*16
    int b   = g >> 15;
    int rem = g & 32767;
    int k   = rem >> 4;
    int grp = rem & 15;
    const float* src = Kg + ((size_t)b * SK_ + k) * D_ + grp * 8;
    float4 x = *(const float4*)(src);
    float4 y = *(const float4*)(src + 4);
    u32x4 w = { pk2(x.x, x.y), pk2(x.z, x.w), pk2(y.x, y.y), pk2(y.z, y.w) };
    int c = (grp * 8) ^ ((k & 7) << 3);
    *(u32x4*)(&Kz[((size_t)b * SK_ + k) * D_ + c]) = w;
}

// ---------------- pre-pass: V -> transposed bf16 tiles, swizzled ----------------
// Vz[b][kt][dv][c] with c = k_local ^ ((dv&7)<<3); tile = 128x64 bf16 = 16KB.
__global__ __launch_bounds__(256)
void prep_v(const float* __restrict__ Vg, u16* __restrict__ Vz)
{
    int g  = blockIdx.x * 256 + threadIdx.x;    // 524288 = 16*32*8*128
    int dv = g & 127;
    int kg = (g >> 7) & 7;
    int kt = (g >> 10) & 31;
    int b  = g >> 15;
    const float* src = Vg + ((size_t)b * SK_ + kt * 64 + kg * 8) * DV_ + dv;
    float v[8];
    #pragma unroll
    for (int jj = 0; jj < 8; ++jj) v[jj] = src[(size_t)jj * DV_];
    u32x4 w = { pk2(v[0], v[1]), pk2(v[2], v[3]), pk2(v[4], v[5]), pk2(v[6], v[7]) };
    int c = (kg * 8) ^ ((dv & 7) << 3);
    *(u32x4*)(&Vz[(((size_t)b * 32 + kt) * 128 + dv) * 64 + c]) = w;
}

// ---------------- main kernel ----------------
// One tile step. KC = current K frags, KN = next-tile K frags (being loaded).
// exp(0.2*s - 12) == exp2(s*0.28853901 - 17.3123405)
#define STEP(IT, KC, KN)                                                      \
  {                                                                           \
    /* pack this tile's mask bits (waits on loads issued last tile) */        \
    u32 mcur = 0;                                                             \
    _Pragma("unroll")                                                         \
    for (int i = 0; i < 16; ++i)                                              \
      mcur |= (mld[i] != 0 ? 1u : 0u) << i;                                   \
    /* reissue mask regs for tile IT+1 (full-tile latency cover) */           \
    if ((IT) + 1 < NT) {                                                      \
      _Pragma("unroll")                                                       \
      for (int qs = 0; qs < 2; ++qs)                                          \
        _Pragma("unroll")                                                     \
        for (int t = 0; t < 2; ++t)                                           \
          _Pragma("unroll")                                                   \
          for (int r = 0; r < 4; ++r)                                         \
            mld[qs * 8 + t * 4 + r] =                                         \
                mbase[(size_t)(qs * 16 + r) * SK_ + ((IT) + 1) * 64 + t * 16];\
    }                                                                         \
    /* V frags for CURRENT tile (L2-hot; consumed after QK^T+softmax) */      \
    s16x8 vc[8];                                                              \
    _Pragma("unroll")                                                         \
    for (int nt = 0; nt < 8; ++nt)                                            \
      vc[nt] = *(const s16x8*)(&Vz[kvbase + (size_t)(IT) * 8192               \
                                   + (nt * 16 + n16) * 64 + vcoff]);          \
    /* K frags for NEXT tile (full-tile cover) */                             \
    if ((IT) + 1 < NT) {                                                      \
      _Pragma("unroll")                                                       \
      for (int t = 0; t < 2; ++t)                                             \
        _Pragma("unroll")                                                     \
        for (int kb = 0; kb < 4; ++kb)                                        \
          KN[t * 4 + kb] = *(const s16x8*)(                                   \
              &Kz[kvbase + (size_t)((IT) + 1) * 8192                          \
                  + (wk * 32 + t * 16 + n16) * 128                            \
                  + ((kb * 32 + quad * 8) ^ kxor)]);                          \
    }                                                                         \
    /* QK^T + softmax per q-subtile (s regs live briefly) */                  \
    _Pragma("unroll")                                                         \
    for (int qs = 0; qs < 2; ++qs) {                                          \
      f32x4 s0 = (f32x4){0.f, 0.f, 0.f, 0.f};                                 \
      f32x4 s1 = (f32x4){0.f, 0.f, 0.f, 0.f};                                 \
      __builtin_amdgcn_s_setprio(1);                                          \
      _Pragma("unroll")                                                       \
      for (int kb = 0; kb < 4; ++kb) {                                        \
        s0 = __builtin_amdgcn_mfma_f32_16x16x32_bf16(aQ[qs][kb], KC[kb],      \
                                                     s0, 0, 0, 0);            \
        s1 = __builtin_amdgcn_mfma_f32_16x16x32_bf16(aQ[qs][kb], KC[4 + kb],  \
                                                     s1, 0, 0, 0);            \
      }                                                                       \
      __builtin_amdgcn_s_setprio(0);                                          \
      _Pragma("unroll")                                                       \
      for (int t = 0; t < 2; ++t)                                             \
        _Pragma("unroll")                                                     \
        for (int r = 0; r < 4; ++r) {                                         \
          float sv = t ? s1[r] : s0[r];                                       \
          float p = __builtin_amdgcn_exp2f(                                   \
              fmaf(sv, 0.28853901f, -17.3123405f));                           \
          l_part[qs][r] += p;                          /* UNmasked denom */   \
          float pv = ((mcur >> (qs * 8 + t * 4 + r)) & 1u) ? p : 0.f;         \
          sh.Ps[wave * 1280 + (qs * 16 + quad * 4 + r) * 40 + t * 16 + n16] = \
              f2bf(pv);                                                       \
        }                                                                     \
    }                                                                         \
    s16x8 aP0 = *(const s16x8*)(&sh.Ps[wave * 1280 + n16 * 40 + quad * 8]);   \
    s16x8 aP1 = *(const s16x8*)(&sh.Ps[wave * 1280 + (16 + n16) * 40 + quad * 8]); \
    __builtin_amdgcn_s_setprio(1);                                            \
    _Pragma("unroll")                                                         \
    for (int nt = 0; nt < 8; ++nt) {                                          \
      o[0][nt] = __builtin_amdgcn_mfma_f32_16x16x32_bf16(aP0, vc[nt],         \
                                                         o[0][nt], 0, 0, 0);  \
      o[1][nt] = __builtin_amdgcn_mfma_f32_16x16x32_bf16(aP1, vc[nt],         \
                                                         o[1][nt], 0, 0, 0);  \
    }                                                                         \
    __builtin_amdgcn_s_setprio(0);                                            \
  }

union ShMem {
    u16 Ps[4 * 32 * 40];                              // 10240 B (loop)
    struct { float oxch[64 * 128]; float lxch[64]; } ep;   // 33024 B (epilogue)
};

__global__ __launch_bounds__(256, 2)
void fattn_main(const float* __restrict__ Qg, const u16* __restrict__ Kz,
                const u16* __restrict__ Vz, const int* __restrict__ Mg,
                float* __restrict__ Og)
{
    __shared__ __align__(16) ShMem sh;   // 33 KB -> LDS no longer the cap

    const int tid  = threadIdx.x;
    const int wave = tid >> 6;
    const int lane = tid & 63;
    const int n16  = lane & 15;
    const int quad = lane >> 4;
    const int wq   = wave & 1;    // q-half: rows wq*32 .. wq*32+31
    const int wk   = wave >> 1;   // k-half: cols wk*32 .. wk*32+31

    // XCD-chunked swizzle (bijective, 512 % 8 == 0): XCD x owns batches
    // {2x,2x+1}; the two co-resident blocks of a CU share a batch.
    const int raw = blockIdx.x;
    const int xcd = raw & 7;
    const int j   = raw >> 3;            // 0..63
    const int b   = xcd * 2 + (j & 1);   // batch
    const int qt  = j >> 1;              // q-tile 0..31
    const int q0  = qt << 6;             // 64 q-rows per block

    // per-lane constant XOR offsets matching the Kz/Vz swizzled layouts
    const int kxor  = (n16 & 7) << 3;
    const int vcoff = (wk * 32 + quad * 8) ^ kxor;

    // ---- Q fragments straight from global (one-time) ----
    s16x8 aQ[2][4];
    #pragma unroll
    for (int qs = 0; qs < 2; ++qs) {
        const float* qsrc = Qg + ((size_t)b * SQ_ + q0 + wq * 32 + qs * 16 + n16) * D_;
        #pragma unroll
        for (int kb = 0; kb < 4; ++kb) {
            float4 x = *(const float4*)(qsrc + kb * 32 + quad * 8);
            float4 y = *(const float4*)(qsrc + kb * 32 + quad * 8 + 4);
            u32x4 w = { pk2(x.x, x.y), pk2(x.z, x.w), pk2(y.x, y.y), pk2(y.z, y.w) };
            aQ[qs][kb] = __builtin_bit_cast(s16x8, w);
        }
    }

    f32x4 o[2][8];
    #pragma unroll
    for (int qs = 0; qs < 2; ++qs)
        #pragma unroll
        for (int i = 0; i < 8; ++i) o[qs][i] = (f32x4){0.f, 0.f, 0.f, 0.f};
    float l_part[2][4] = {{0.f, 0.f, 0.f, 0.f}, {0.f, 0.f, 0.f, 0.f}};

    const size_t kvbase = (size_t)b * 262144;   // per-batch slab (u16 elems)
    const int* mbase = Mg + ((size_t)(b * SQ_ + q0 + wq * 32 + quad * 4)) * SK_
                     + wk * 32 + n16;

    // ---- prologue: tile-0 K frags + tile-0 mask loads (no barrier!) ----
    s16x8 k0[8], k1[8];
    #pragma unroll
    for (int t = 0; t < 2; ++t)
        #pragma unroll
        for (int kb = 0; kb < 4; ++kb)
            k0[t * 4 + kb] = *(const s16x8*)(
                &Kz[kvbase + (wk * 32 + t * 16 + n16) * 128
                    + ((kb * 32 + quad * 8) ^ kxor)]);
    int mld[16];
    #pragma unroll
    for (int qs = 0; qs < 2; ++qs)
        #pragma unroll
        for (int t = 0; t < 2; ++t)
            #pragma unroll
            for (int r = 0; r < 4; ++r)
                mld[qs * 8 + t * 4 + r] = mbase[(size_t)(qs * 16 + r) * SK_ + t * 16];

    for (int it = 0; it < NT; it += 2) {
        STEP(it,     k0, k1)
        STEP(it + 1, k1, k0)
    }

    // ---- epilogue: reduce l across n16 lanes; combine wk halves ----
    float lr[2][4];
    #pragma unroll
    for (int qs = 0; qs < 2; ++qs)
        #pragma unroll
        for (int r = 0; r < 4; ++r) {
            float l = l_part[qs][r];
            #pragma unroll
            for (int off = 1; off < 16; off <<= 1) l += __shfl_xor(l, off);
            lr[qs][r] = l;
        }
    __syncthreads();   // all waves done with Ps before oxch overlay
    if (wk == 1) {
        #pragma unroll
        for (int qs = 0; qs < 2; ++qs)
            #pragma unroll
            for (int r = 0; r < 4; ++r) {
                int row = wq * 32 + qs * 16 + quad * 4 + r;
                #pragma unroll
                for (int nt = 0; nt < 8; ++nt)
                    sh.ep.oxch[row * 128 + nt * 16 + n16] = o[qs][nt][r];
                if (n16 == 0) sh.ep.lxch[row] = lr[qs][r];
            }
    }
    __syncthreads();
    if (wk == 0) {
        const float ksc = 1.0f / 0.9f;
        #pragma unroll
        for (int qs = 0; qs < 2; ++qs)
            #pragma unroll
            for (int r = 0; r < 4; ++r) {
                int row = wq * 32 + qs * 16 + quad * 4 + r;
                float inv = ksc / (lr[qs][r] + sh.ep.lxch[row]);
                size_t ob = ((size_t)b * SQ_ + q0 + row) * (size_t)DV_;
                #pragma unroll
                for (int nt = 0; nt < 8; ++nt)
                    Og[ob + nt * 16 + n16] =
                        (o[qs][nt][r] + sh.ep.oxch[row * 128 + nt * 16 + n16]) * inv;
            }
    }
}

// ---------------- fallback (R4 kernel, used only if workspace too small) ----------------
#define BQ_FB 64
#define LDQ  136
#define LDK  136
#define LDVT 72
#define LDP  72

__global__ __launch_bounds__(256, 2)
void fattn_fb(const float* __restrict__ Qg, const float* __restrict__ Kg,
              const float* __restrict__ Vg, const int* __restrict__ Mg,
              float* __restrict__ Og)
{
    __shared__ u16 Qs[BQ_FB * LDQ];
    __shared__ u16 Ks[BK * LDK];
    __shared__ u16 Vt[DV_ * LDVT];
    __shared__ u16 Ps[4 * 16 * LDP];

    const int tid  = threadIdx.x;
    const int wave = tid >> 6;
    const int lane = tid & 63;
    const int n16  = lane & 15;
    const int quad = lane >> 4;

    const int raw = blockIdx.x;
    const int xcd = raw & 7;
    const int j   = raw >> 3;
    const int b   = xcd * 2 + (j & 1);
    const int q0  = (j >> 1) << 6;

    const int srow = tid >> 4;
    const int scol = (tid & 15) * 8;
    const int vrot = (tid & 7) * 8;

    {
        const float* src = Qg + ((size_t)b * SQ_ + q0) * D_;
        #pragma unroll
        for (int c = 0; c < 4; ++c) {
            int row = c * 16 + srow;
            float4 v0 = *(const float4*)(&src[row * D_ + scol]);
            float4 v1 = *(const float4*)(&src[row * D_ + scol + 4]);
            uint4 pk = { pk2(v0.x, v0.y), pk2(v0.z, v0.w),
                         pk2(v1.x, v1.y), pk2(v1.z, v1.w) };
            *(uint4*)(&Qs[row * LDQ + scol]) = pk;
        }
    }
    __syncthreads();

    s16x8 aQ[4];
    {
        const int qr = wave * 16 + n16;
        #pragma unroll
        for (int kb = 0; kb < 4; ++kb)
            aQ[kb] = *(const s16x8*)(&Qs[qr * LDQ + kb * 32 + quad * 8]);
    }

    f32x4 o[8];
    #pragma unroll
    for (int i = 0; i < 8; ++i) o[i] = (f32x4){0.f, 0.f, 0.f, 0.f};
    float l_part[4] = {0.f, 0.f, 0.f, 0.f};

    const size_t mask_qbase = ((size_t)b * SQ_ + q0 + wave * 16 + quad * 4) * (size_t)SK_;
    const float* baseK = Kg + ((size_t)b * SK_) * D_;
    const float* baseV = Vg + ((size_t)b * SK_) * DV_;

    float4 kf[8], vf[8];
    #pragma unroll
    for (int c = 0; c < 4; ++c) {
        int row = c * 16 + srow;
        kf[2*c]   = *(const float4*)(&baseK[row * D_ + scol]);
        kf[2*c+1] = *(const float4*)(&baseK[row * D_ + scol + 4]);
        vf[2*c]   = *(const float4*)(&baseV[row * DV_ + scol]);
        vf[2*c+1] = *(const float4*)(&baseV[row * DV_ + scol + 4]);
    }
    int mkc[4][4], mkn[4][4];
    #pragma unroll
    for (int t = 0; t < 4; ++t)
        #pragma unroll
        for (int r = 0; r < 4; ++r)
            mkc[t][r] = Mg[mask_qbase + (size_t)r * SK_ + (t * 16 + n16)];

    for (int it = 0; it < NT; ++it) {
        __syncthreads();
        #pragma unroll
        for (int c = 0; c < 4; ++c) {
            int row = c * 16 + srow;
            uint4 pk = { pk2(kf[2*c].x, kf[2*c].y),     pk2(kf[2*c].z, kf[2*c].w),
                         pk2(kf[2*c+1].x, kf[2*c+1].y), pk2(kf[2*c+1].z, kf[2*c+1].w) };
            *(uint4*)(&Ks[row * LDK + scol]) = pk;
        }
        #pragma unroll
        for (int c = 0; c < 4; ++c) {
            int k    = c * 16 + srow;
            int rcol = (k + vrot) & 63;
            int dv0  = scol;
            u32 r0 = pk2(vf[2*c].x,   vf[2*c].y);
            u32 r1 = pk2(vf[2*c].z,   vf[2*c].w);
            u32 r2 = pk2(vf[2*c+1].x, vf[2*c+1].y);
            u32 r3 = pk2(vf[2*c+1].z, vf[2*c+1].w);
            Vt[(dv0 + 0) * LDVT + rcol] = (u16)r0;
            Vt[(dv0 + 1) * LDVT + rcol] = (u16)(r0 >> 16);
            Vt[(dv0 + 2) * LDVT + rcol] = (u16)r1;
            Vt[(dv0 + 3) * LDVT + rcol] = (u16)(r1 >> 16);
            Vt[(dv0 + 4) * LDVT + rcol] = (u16)r2;
            Vt[(dv0 + 5) * LDVT + rcol] = (u16)(r2 >> 16);
            Vt[(dv0 + 6) * LDVT + rcol] = (u16)r3;
            Vt[(dv0 + 7) * LDVT + rcol] = (u16)(r3 >> 16);
        }
        if (it + 1 < NT) {
            const int k0n = (it + 1) * BK;
            #pragma unroll
            for (int c = 0; c < 4; ++c) {
                int row = k0n + c * 16 + srow;
                kf[2*c]   = *(const float4*)(&baseK[row * D_ + scol]);
                kf[2*c+1] = *(const float4*)(&baseK[row * D_ + scol + 4]);
                vf[2*c]   = *(const float4*)(&baseV[row * DV_ + scol]);
                vf[2*c+1] = *(const float4*)(&baseV[row * DV_ + scol + 4]);
            }
            #pragma unroll
            for (int t = 0; t < 4; ++t)
                #pragma unroll
                for (int r = 0; r < 4; ++r)
                    mkn[t][r] = Mg[mask_qbase + (size_t)r * SK_ + (k0n + t * 16 + n16)];
        }
        __syncthreads();

        f32x4 s[4];
        #pragma unroll
        for (int t = 0; t < 4; ++t) s[t] = (f32x4){0.f, 0.f, 0.f, 0.f};
        #pragma unroll
        for (int kb = 0; kb < 4; ++kb) {
            #pragma unroll
            for (int t = 0; t < 4; ++t) {
                s16x8 bK = *(const s16x8*)(&Ks[(t * 16 + n16) * LDK + kb * 32 + quad * 8]);
                s[t] = __builtin_amdgcn_mfma_f32_16x16x32_bf16(aQ[kb], bK, s[t], 0, 0, 0);
            }
        }
        #pragma unroll
        for (int t = 0; t < 4; ++t)
            #pragma unroll
            for (int r = 0; r < 4; ++r) {
                float p = __expf(fmaf(s[t][r], 0.2f, -12.0f));
                l_part[r] += p;
                float pv = mkc[t][r] ? p : 0.f;
                Ps[(wave * 16 + quad * 4 + r) * LDP + t * 16 + n16] = f2bf(pv);
            }
        #pragma unroll
        for (int kk = 0; kk < 2; ++kk) {
            s16x8 aP = *(const s16x8*)(&Ps[(wave * 16 + n16) * LDP + kk * 32 + quad * 8]);
            #pragma unroll
            for (int nt = 0; nt < 8; ++nt) {
                int dv   = nt * 16 + n16;
                int rcol = (kk * 32 + quad * 8 + 8 * ((dv >> 3) & 7)) & 63;
                s16x8 bV = *(const s16x8*)(&Vt[dv * LDVT + rcol]);
                o[nt] = __builtin_amdgcn_mfma_f32_16x16x32_bf16(aP, bV, o[nt], 0, 0, 0);
            }
        }
        #pragma unroll
        for (int t = 0; t < 4; ++t)
            #pragma unroll
            for (int r = 0; r < 4; ++r) mkc[t][r] = mkn[t][r];
    }

    const float keep_scale = 1.0f / 0.9f;
    #pragma unroll
    for (int r = 0; r < 4; ++r) {
        float l = l_part[r];
        #pragma unroll
        for (int off = 1; off < 16; off <<= 1)
            l += __shfl_xor(l, off);
        float inv_l = keep_scale / l;
        size_t obase = ((size_t)b * SQ_ + q0 + wave * 16 + quad * 4 + r) * DV_;
        #pragma unroll
        for (int nt = 0; nt < 8; ++nt)
            Og[obase + nt * 16 + n16] = o[nt][r] * inv_l;
    }
}

extern "C" void kernel_launch(void* const* d_in, const int* in_sizes, int n_in,
                              void* d_out, int out_size, void* d_ws, size_t ws_size,
                              hipStream_t stream) {
    const float* Qg = (const float*)d_in[0];
    const float* Kg = (const float*)d_in[1];
    const float* Vg = (const float*)d_in[2];
    const int*   Mg = (const int*)d_in[3];
    float* Og = (float*)d_out;
    if (d_ws != nullptr && ws_size >= (size_t)16 * 1024 * 1024) {
        u16* Kz = (u16*)d_ws;                   // 8 MB swizzled bf16 K
        u16* Vz = Kz + 4194304;                 // 8 MB transposed+swizzled bf16 V
        prep_k<<<dim3(2048), 256, 0, stream>>>(Kg, Kz);
        prep_v<<<dim3(2048), 256, 0, stream>>>(Vg, Vz);
        fattn_main<<<dim3(512), 256, 0, stream>>>(Qg, Kz, Vz, Mg, Og);
    } else {
        fattn_fb<<<dim3(512), 256, 0, stream>>>(Qg, Kg, Vg, Mg, Og);
    }
}

// Round 8
// 481.265 us; speedup vs baseline: 1.6005x; 1.6005x over previous
//
#include <hip/hip_runtime.h>
#include <stdint.h>

// Fused attention: S=(x1@x2^T)*0.2; P=softmax(S); P=mask?P/0.9:0; O=P@x3
// B=16, SQ=SK=2048, D=DV=128. fp32 in/out, int32 mask, bf16 MFMA compute.
//
// R11 == R10 resubmitted verbatim (R10 bench was an infra failure: container
// acquisition failed twice; kernel never ran. One variable per round: retry).
//
// R10 vs R9 (472us main: VGPR blowout -> 753MB scratch spill; but PASSED =>
// register-fragment addressing from swizzled global layouts is verified):
//  Revert to R8 shell (124us main, proven), graft in ONLY the K half of R9:
//  1. K in registers: k0/k1 ping-pong (64 VGPR), loaded one tile ahead
//     straight from L2-resident Kz with R9's verified address math. Removes
//     8 ds_read_b128/wave/tile AND halves gload_lds staging (16KB/tile).
//  2. V stays in LDS (R8's double-buffered global_load_lds, one barrier per
//     tile). LDS: 43KB (Vbuf 32K + Ps 10K + lxch). LDS pipe ~2900 -> ~2000
//     cyc/tile/CU.
//  3. Masks: R8 ping-pong but bit-packed at consume (R9-verified) -> 16 live
//     regs not 32; NONTEMPORAL loads so the 268MB one-shot mask stream
//     doesn't evict L2-resident Kz/Vz (the K-reg path depends on L2 hits).
//  VGPR ~210 < 256 cap -> no spill (R9's ~280 spilled).
//  Carried: 64q x 64k / 4 waves; prep_k/prep_v pre-passes; XCD swizzle;
//  exp2 static-max softmax; cvt_pk; setprio; cross-wk epilogue via oxch.
//  Fallback (ws < 16MB): R4 kernel.

#define B_   16
#define SQ_  2048
#define SK_  2048
#define D_   128
#define DV_  128
#define BK   64
#define NT   (SK_ / BK)   // 32 tiles

typedef short  s16x8 __attribute__((ext_vector_type(8)));   // MFMA A/B frag
typedef float  f32x4 __attribute__((ext_vector_type(4)));   // MFMA C/D frag
typedef unsigned int u32x4 __attribute__((ext_vector_type(4)));
typedef unsigned short u16;
typedef unsigned int   u32;

// f32 pair -> packed bf16x2, RNE, single instruction (no builtin on gfx950).
__device__ __forceinline__ u32 pk2(float a, float b) {
    u32 r;
    asm("v_cvt_pk_bf16_f32 %0, %1, %2" : "=v"(r) : "v"(a), "v"(b));
    return r;
}
__device__ __forceinline__ u16 f2bf(float f) { return (u16)pk2(f, 0.0f); }

// async global->LDS, 16B per lane. dst = wave-uniform base (HW adds lane*16).
__device__ __forceinline__ void gload16(void* lds, const void* g) {
    __builtin_amdgcn_global_load_lds((const __attribute__((address_space(1))) u32*)g,
                                     (__attribute__((address_space(3))) u32*)lds,
                                     16, 0, 0);
}

// ---------------- pre-pass: K -> bf16, bank-swizzled ----------------
// Kz[b][k][c] with c = col ^ ((k&7)<<3). 8 MB.
__global__ __launch_bounds__(256)
void prep_k(const float* __restrict__ Kg, u16* __restrict__ Kz)
{
    int g   = blockIdx.x * 256 + threadIdx.x;   // 524288 = 16*2048*16
    int b   = g >> 15;
    int rem = g & 32767;
    int k   = rem >> 4;
    int grp = rem & 15;
    const float* src = Kg + ((size_t)b * SK_ + k) * D_ + grp * 8;
    float4 x = *(const float4*)(src);
    float4 y = *(const float4*)(src + 4);
    u32x4 w = { pk2(x.x, x.y), pk2(x.z, x.w), pk2(y.x, y.y), pk2(y.z, y.w) };
    int c = (grp * 8) ^ ((k & 7) << 3);
    *(u32x4*)(&Kz[((size_t)b * SK_ + k) * D_ + c]) = w;
}

// ---------------- pre-pass: V -> transposed bf16 tiles, swizzled ----------------
// Vz[b][kt][dv][c] with c = k_local ^ ((dv&7)<<3); tile = 128x64 bf16 = 16KB.
__global__ __launch_bounds__(256)
void prep_v(const float* __restrict__ Vg, u16* __restrict__ Vz)
{
    int g  = blockIdx.x * 256 + threadIdx.x;    // 524288 = 16*32*8*128
    int dv = g & 127;
    int kg = (g >> 7) & 7;
    int kt = (g >> 10) & 31;
    int b  = g >> 15;
    const float* src = Vg + ((size_t)b * SK_ + kt * 64 + kg * 8) * DV_ + dv;
    float v[8];
    #pragma unroll
    for (int jj = 0; jj < 8; ++jj) v[jj] = src[(size_t)jj * DV_];
    u32x4 w = { pk2(v[0], v[1]), pk2(v[2], v[3]), pk2(v[4], v[5]), pk2(v[6], v[7]) };
    int c = (kg * 8) ^ ((dv & 7) << 3);
    *(u32x4*)(&Vz[(((size_t)b * 32 + kt) * 128 + dv) * 64 + c]) = w;
}

// ---------------- main kernel ----------------
// One tile step. CUR/NXT: V LDS buffers; KC/KN: K reg ping-pong.
// exp(0.2*s - 12) == exp2(s*0.28853901 - 17.3123405)
#define STEP(IT, CUR, NXT, KC, KN)                                            \
  {                                                                           \
    /* pack this tile's mask bits (waits on loads issued last tile) */        \
    u32 mcur = 0;                                                             \
    _Pragma("unroll")                                                         \
    for (int i = 0; i < 16; ++i)                                              \
      mcur |= (mld[i] != 0 ? 1u : 0u) << i;                                   \
    if ((IT) + 1 < NT) {                                                      \
      /* V staging for IT+1 (async -> LDS) */                                 \
      const u16* Vt = Vz + kvbase + (size_t)((IT) + 1) * 8192;                \
      _Pragma("unroll")                                                       \
      for (int i = 0; i < 4; ++i) {                                           \
        int c16 = (wave * 4 + i) * 512;                                       \
        gload16(&Vbuf[NXT][c16], &Vt[c16 + lane * 8]);                        \
      }                                                                       \
      /* K frags for IT+1 -> regs (L2-hot; full-tile latency cover) */        \
      _Pragma("unroll")                                                       \
      for (int t = 0; t < 2; ++t)                                             \
        _Pragma("unroll")                                                     \
        for (int kb = 0; kb < 4; ++kb)                                        \
          KN[t * 4 + kb] = *(const s16x8*)(                                   \
              &Kz[kvbase + (size_t)((IT) + 1) * 8192                          \
                  + (wk * 32 + t * 16 + n16) * 128                            \
                  + ((kb * 32 + quad * 8) ^ kxor)]);                          \
      /* mask regs for IT+1 (nontemporal: don't evict Kz/Vz from L2) */       \
      _Pragma("unroll")                                                       \
      for (int qs = 0; qs < 2; ++qs)                                          \
        _Pragma("unroll")                                                     \
        for (int t = 0; t < 2; ++t)                                           \
          _Pragma("unroll")                                                   \
          for (int r = 0; r < 4; ++r)                                         \
            mld[qs * 8 + t * 4 + r] = __builtin_nontemporal_load(             \
                &mbase[(size_t)(qs * 16 + r) * SK_ + ((IT) + 1) * 64 + t * 16]); \
    }                                                                         \
    f32x4 s[2][2];                                                            \
    _Pragma("unroll")                                                         \
    for (int qs = 0; qs < 2; ++qs)                                            \
      _Pragma("unroll")                                                       \
      for (int t = 0; t < 2; ++t) s[qs][t] = (f32x4){0.f, 0.f, 0.f, 0.f};     \
    __builtin_amdgcn_s_setprio(1);                                            \
    _Pragma("unroll")                                                         \
    for (int kb = 0; kb < 4; ++kb) {                                          \
      _Pragma("unroll")                                                       \
      for (int t = 0; t < 2; ++t) {                                           \
        _Pragma("unroll")                                                     \
        for (int qs = 0; qs < 2; ++qs)                                        \
          s[qs][t] = __builtin_amdgcn_mfma_f32_16x16x32_bf16(                 \
              aQ[qs][kb], KC[t * 4 + kb], s[qs][t], 0, 0, 0);                 \
      }                                                                       \
    }                                                                         \
    __builtin_amdgcn_s_setprio(0);                                            \
    _Pragma("unroll")                                                         \
    for (int qs = 0; qs < 2; ++qs)                                            \
      _Pragma("unroll")                                                       \
      for (int t = 0; t < 2; ++t)                                             \
        _Pragma("unroll")                                                     \
        for (int r = 0; r < 4; ++r) {                                         \
          float p = __builtin_amdgcn_exp2f(                                   \
              fmaf(s[qs][t][r], 0.28853901f, -17.3123405f));                  \
          l_part[qs][r] += p;                          /* UNmasked denom */   \
          float pv = ((mcur >> (qs * 8 + t * 4 + r)) & 1u) ? p : 0.f;         \
          Ps[wave * 1280 + (qs * 16 + quad * 4 + r) * 40 + t * 16 + n16] =    \
              f2bf(pv);                                                       \
        }                                                                     \
    s16x8 aP0 = *(const s16x8*)(&Ps[wave * 1280 + n16 * 40 + quad * 8]);      \
    s16x8 aP1 = *(const s16x8*)(&Ps[wave * 1280 + (16 + n16) * 40 + quad * 8]); \
    __builtin_amdgcn_s_setprio(1);                                            \
    _Pragma("unroll")                                                         \
    for (int nt = 0; nt < 8; ++nt) {                                          \
      s16x8 bV = *(const s16x8*)(&Vbuf[CUR][(nt * 16 + n16) * 64 + vcoff]);   \
      o[0][nt] = __builtin_amdgcn_mfma_f32_16x16x32_bf16(aP0, bV, o[0][nt], 0, 0, 0); \
      o[1][nt] = __builtin_amdgcn_mfma_f32_16x16x32_bf16(aP1, bV, o[1][nt], 0, 0, 0); \
    }                                                                         \
    __builtin_amdgcn_s_setprio(0);                                            \
    __syncthreads();   /* NXT V staged + visible; K/mask loads also drained */ \
  }

__global__ __launch_bounds__(256, 2)
void fattn_main(const float* __restrict__ Qg, const u16* __restrict__ Kz,
                const u16* __restrict__ Vz, const int* __restrict__ Mg,
                float* __restrict__ Og)
{
    __shared__ __align__(16) u16 Vbuf[2][128 * 64];   // 32768 B (epilogue: oxch)
    __shared__ __align__(16) u16 Ps[4 * 32 * 40];     // 10240 B
    __shared__ float lxch[64];                        //   256 B
    // 43264 B total

    const int tid  = threadIdx.x;
    const int wave = tid >> 6;
    const int lane = tid & 63;
    const int n16  = lane & 15;
    const int quad = lane >> 4;
    const int wq   = wave & 1;    // q-half: rows wq*32 .. wq*32+31
    const int wk   = wave >> 1;   // k-half: cols wk*32 .. wk*32+31

    // XCD-chunked swizzle (bijective, 512 % 8 == 0)
    const int raw = blockIdx.x;
    const int xcd = raw & 7;
    const int j   = raw >> 3;            // 0..63
    const int b   = xcd * 2 + (j & 1);   // batch
    const int qt  = j >> 1;              // q-tile 0..31
    const int q0  = qt << 6;             // 64 q-rows per block

    const int kxor  = (n16 & 7) << 3;                 // swizzle XOR (u16 units)
    const int vcoff = (wk * 32 + quad * 8) ^ kxor;    // V-frag col offset

    // ---- Q fragments straight from global (one-time) ----
    s16x8 aQ[2][4];
    #pragma unroll
    for (int qs = 0; qs < 2; ++qs) {
        const float* qsrc = Qg + ((size_t)b * SQ_ + q0 + wq * 32 + qs * 16 + n16) * D_;
        #pragma unroll
        for (int kb = 0; kb < 4; ++kb) {
            float4 x = *(const float4*)(qsrc + kb * 32 + quad * 8);
            float4 y = *(const float4*)(qsrc + kb * 32 + quad * 8 + 4);
            u32x4 w = { pk2(x.x, x.y), pk2(x.z, x.w), pk2(y.x, y.y), pk2(y.z, y.w) };
            aQ[qs][kb] = __builtin_bit_cast(s16x8, w);
        }
    }

    f32x4 o[2][8];
    #pragma unroll
    for (int qs = 0; qs < 2; ++qs)
        #pragma unroll
        for (int i = 0; i < 8; ++i) o[qs][i] = (f32x4){0.f, 0.f, 0.f, 0.f};
    float l_part[2][4] = {{0.f, 0.f, 0.f, 0.f}, {0.f, 0.f, 0.f, 0.f}};

    const size_t kvbase = (size_t)b * 262144;   // per-batch slab (u16 elems)
    const int* mbase = Mg + ((size_t)(b * SQ_ + q0 + wq * 32 + quad * 4)) * SK_
                     + wk * 32 + n16;

    // ---- prologue: V tile 0 -> LDS, K tile 0 -> regs, mask tile 0 -> regs ----
    {
        const u16* Vt = Vz + kvbase;
        #pragma unroll
        for (int i = 0; i < 4; ++i) {
            int c16 = (wave * 4 + i) * 512;
            gload16(&Vbuf[0][c16], &Vt[c16 + lane * 8]);
        }
    }
    s16x8 k0[8], k1[8];
    #pragma unroll
    for (int t = 0; t < 2; ++t)
        #pragma unroll
        for (int kb = 0; kb < 4; ++kb)
            k0[t * 4 + kb] = *(const s16x8*)(
                &Kz[kvbase + (wk * 32 + t * 16 + n16) * 128
                    + ((kb * 32 + quad * 8) ^ kxor)]);
    int mld[16];
    #pragma unroll
    for (int qs = 0; qs < 2; ++qs)
        #pragma unroll
        for (int t = 0; t < 2; ++t)
            #pragma unroll
            for (int r = 0; r < 4; ++r)
                mld[qs * 8 + t * 4 + r] = __builtin_nontemporal_load(
                    &mbase[(size_t)(qs * 16 + r) * SK_ + t * 16]);

    __syncthreads();   // tile 0 V staged + visible

    for (int it = 0; it < NT; it += 2) {
        STEP(it,     0, 1, k0, k1)
        STEP(it + 1, 1, 0, k1, k0)
    }

    // ---- epilogue: reduce l across n16 lanes; combine wk halves ----
    float lr[2][4];
    #pragma unroll
    for (int qs = 0; qs < 2; ++qs)
        #pragma unroll
        for (int r = 0; r < 4; ++r) {
            float l = l_part[qs][r];
            #pragma unroll
            for (int off = 1; off < 16; off <<= 1) l += __shfl_xor(l, off);
            lr[qs][r] = l;
        }
    float* oxch = (float*)Vbuf;   // 64 x 128 f32 = 32768 B, exact fit
    if (wk == 1) {
        #pragma unroll
        for (int qs = 0; qs < 2; ++qs)
            #pragma unroll
            for (int r = 0; r < 4; ++r) {
                int row = wq * 32 + qs * 16 + quad * 4 + r;
                #pragma unroll
                for (int nt = 0; nt < 8; ++nt)
                    oxch[row * 128 + nt * 16 + n16] = o[qs][nt][r];
                if (n16 == 0) lxch[row] = lr[qs][r];
            }
    }
    __syncthreads();
    if (wk == 0) {
        const float ksc = 1.0f / 0.9f;
        #pragma unroll
        for (int qs = 0; qs < 2; ++qs)
            #pragma unroll
            for (int r = 0; r < 4; ++r) {
                int row = wq * 32 + qs * 16 + quad * 4 + r;
                float inv = ksc / (lr[qs][r] + lxch[row]);
                size_t ob = ((size_t)b * SQ_ + q0 + row) * (size_t)DV_;
                #pragma unroll
                for (int nt = 0; nt < 8; ++nt)
                    Og[ob + nt * 16 + n16] =
                        (o[qs][nt][r] + oxch[row * 128 + nt * 16 + n16]) * inv;
            }
    }
}

// ---------------- fallback (R4 kernel, used only if workspace too small) ----------------
#define BQ_FB 64
#define LDQ  136
#define LDK  136
#define LDVT 72
#define LDP  72

__global__ __launch_bounds__(256, 2)
void fattn_fb(const float* __restrict__ Qg, const float* __restrict__ Kg,
              const float* __restrict__ Vg, const int* __restrict__ Mg,
              float* __restrict__ Og)
{
    __shared__ u16 Qs[BQ_FB * LDQ];
    __shared__ u16 Ks[BK * LDK];
    __shared__ u16 Vt[DV_ * LDVT];
    __shared__ u16 Ps[4 * 16 * LDP];

    const int tid  = threadIdx.x;
    const int wave = tid >> 6;
    const int lane = tid & 63;
    const int n16  = lane & 15;
    const int quad = lane >> 4;

    const int raw = blockIdx.x;
    const int xcd = raw & 7;
    const int j   = raw >> 3;
    const int b   = xcd * 2 + (j & 1);
    const int q0  = (j >> 1) << 6;

    const int srow = tid >> 4;
    const int scol = (tid & 15) * 8;
    const int vrot = (tid & 7) * 8;

    {
        const float* src = Qg + ((size_t)b * SQ_ + q0) * D_;
        #pragma unroll
        for (int c = 0; c < 4; ++c) {
            int row = c * 16 + srow;
            float4 v0 = *(const float4*)(&src[row * D_ + scol]);
            float4 v1 = *(const float4*)(&src[row * D_ + scol + 4]);
            uint4 pk = { pk2(v0.x, v0.y), pk2(v0.z, v0.w),
                         pk2(v1.x, v1.y), pk2(v1.z, v1.w) };
            *(uint4*)(&Qs[row * LDQ + scol]) = pk;
        }
    }
    __syncthreads();

    s16x8 aQ[4];
    {
        const int qr = wave * 16 + n16;
        #pragma unroll
        for (int kb = 0; kb < 4; ++kb)
            aQ[kb] = *(const s16x8*)(&Qs[qr * LDQ + kb * 32 + quad * 8]);
    }

    f32x4 o[8];
    #pragma unroll
    for (int i = 0; i < 8; ++i) o[i] = (f32x4){0.f, 0.f, 0.f, 0.f};
    float l_part[4] = {0.f, 0.f, 0.f, 0.f};

    const size_t mask_qbase = ((size_t)b * SQ_ + q0 + wave * 16 + quad * 4) * (size_t)SK_;
    const float* baseK = Kg + ((size_t)b * SK_) * D_;
    const float* baseV = Vg + ((size_t)b * SK_) * DV_;

    float4 kf[8], vf[8];
    #pragma unroll
    for (int c = 0; c < 4; ++c) {
        int row = c * 16 + srow;
        kf[2*c]   = *(const float4*)(&baseK[row * D_ + scol]);
        kf[2*c+1] = *(const float4*)(&baseK[row * D_ + scol + 4]);
        vf[2*c]   = *(const float4*)(&baseV[row * DV_ + scol]);
        vf[2*c+1] = *(const float4*)(&baseV[row * DV_ + scol + 4]);
    }
    int mkc[4][4], mkn[4][4];
    #pragma unroll
    for (int t = 0; t < 4; ++t)
        #pragma unroll
        for (int r = 0; r < 4; ++r)
            mkc[t][r] = Mg[mask_qbase + (size_t)r * SK_ + (t * 16 + n16)];

    for (int it = 0; it < NT; ++it) {
        __syncthreads();
        #pragma unroll
        for (int c = 0; c < 4; ++c) {
            int row = c * 16 + srow;
            uint4 pk = { pk2(kf[2*c].x, kf[2*c].y),     pk2(kf[2*c].z, kf[2*c].w),
                         pk2(kf[2*c+1].x, kf[2*c+1].y), pk2(kf[2*c+1].z, kf[2*c+1].w) };
            *(uint4*)(&Ks[row * LDK + scol]) = pk;
        }
        #pragma unroll
        for (int c = 0; c < 4; ++c) {
            int k    = c * 16 + srow;
            int rcol = (k + vrot) & 63;
            int dv0  = scol;
            u32 r0 = pk2(vf[2*c].x,   vf[2*c].y);
            u32 r1 = pk2(vf[2*c].z,   vf[2*c].w);
            u32 r2 = pk2(vf[2*c+1].x, vf[2*c+1].y);
            u32 r3 = pk2(vf[2*c+1].z, vf[2*c+1].w);
            Vt[(dv0 + 0) * LDVT + rcol] = (u16)r0;
            Vt[(dv0 + 1) * LDVT + rcol] = (u16)(r0 >> 16);
            Vt[(dv0 + 2) * LDVT + rcol] = (u16)r1;
            Vt[(dv0 + 3) * LDVT + rcol] = (u16)(r1 >> 16);
            Vt[(dv0 + 4) * LDVT + rcol] = (u16)r2;
            Vt[(dv0 + 5) * LDVT + rcol] = (u16)(r2 >> 16);
            Vt[(dv0 + 6) * LDVT + rcol] = (u16)r3;
            Vt[(dv0 + 7) * LDVT + rcol] = (u16)(r3 >> 16);
        }
        if (it + 1 < NT) {
            const int k0n = (it + 1) * BK;
            #pragma unroll
            for (int c = 0; c < 4; ++c) {
                int row = k0n + c * 16 + srow;
                kf[2*c]   = *(const float4*)(&baseK[row * D_ + scol]);
                kf[2*c+1] = *(const float4*)(&baseK[row * D_ + scol + 4]);
                vf[2*c]   = *(const float4*)(&baseV[row * DV_ + scol]);
                vf[2*c+1] = *(const float4*)(&baseV[row * DV_ + scol + 4]);
            }
            #pragma unroll
            for (int t = 0; t < 4; ++t)
                #pragma unroll
                for (int r = 0; r < 4; ++r)
                    mkn[t][r] = Mg[mask_qbase + (size_t)r * SK_ + (k0n + t * 16 + n16)];
        }
        __syncthreads();

        f32x4 s[4];
        #pragma unroll
        for (int t = 0; t < 4; ++t) s[t] = (f32x4){0.f, 0.f, 0.f, 0.f};
        #pragma unroll
        for (int kb = 0; kb < 4; ++kb) {
            #pragma unroll
            for (int t = 0; t < 4; ++t) {
                s16x8 bK = *(const s16x8*)(&Ks[(t * 16 + n16) * LDK + kb * 32 + quad * 8]);
                s[t] = __builtin_amdgcn_mfma_f32_16x16x32_bf16(aQ[kb], bK, s[t], 0, 0, 0);
            }
        }
        #pragma unroll
        for (int t = 0; t < 4; ++t)
            #pragma unroll
            for (int r = 0; r < 4; ++r) {
                float p = __expf(fmaf(s[t][r], 0.2f, -12.0f));
                l_part[r] += p;
                float pv = mkc[t][r] ? p : 0.f;
                Ps[(wave * 16 + quad * 4 + r) * LDP + t * 16 + n16] = f2bf(pv);
            }
        #pragma unroll
        for (int kk = 0; kk < 2; ++kk) {
            s16x8 aP = *(const s16x8*)(&Ps[(wave * 16 + n16) * LDP + kk * 32 + quad * 8]);
            #pragma unroll
            for (int nt = 0; nt < 8; ++nt) {
                int dv   = nt * 16 + n16;
                int rcol = (kk * 32 + quad * 8 + 8 * ((dv >> 3) & 7)) & 63;
                s16x8 bV = *(const s16x8*)(&Vt[dv * LDVT + rcol]);
                o[nt] = __builtin_amdgcn_mfma_f32_16x16x32_bf16(aP, bV, o[nt], 0, 0, 0);
            }
        }
        #pragma unroll
        for (int t = 0; t < 4; ++t)
            #pragma unroll
            for (int r = 0; r < 4; ++r) mkc[t][r] = mkn[t][r];
    }

    const float keep_scale = 1.0f / 0.9f;
    #pragma unroll
    for (int r = 0; r < 4; ++r) {
        float l = l_part[r];
        #pragma unroll
        for (int off = 1; off < 16; off <<= 1)
            l += __shfl_xor(l, off);
        float inv_l = keep_scale / l;
        size_t obase = ((size_t)b * SQ_ + q0 + wave * 16 + quad * 4 + r) * DV_;
        #pragma unroll
        for (int nt = 0; nt < 8; ++nt)
            Og[obase + nt * 16 + n16] = o[nt][r] * inv_l;
    }
}

extern "C" void kernel_launch(void* const* d_in, const int* in_sizes, int n_in,
                              void* d_out, int out_size, void* d_ws, size_t ws_size,
                              hipStream_t stream) {
    const float* Qg = (const float*)d_in[0];
    const float* Kg = (const float*)d_in[1];
    const float* Vg = (const float*)d_in[2];
    const int*   Mg = (const int*)d_in[3];
    float* Og = (float*)d_out;
    if (d_ws != nullptr && ws_size >= (size_t)16 * 1024 * 1024) {
        u16* Kz = (u16*)d_ws;                   // 8 MB swizzled bf16 K
        u16* Vz = Kz + 4194304;                 // 8 MB transposed+swizzled bf16 V
        prep_k<<<dim3(2048), 256, 0, stream>>>(Kg, Kz);
        prep_v<<<dim3(2048), 256, 0, stream>>>(Vg, Vz);
        fattn_main<<<dim3(512), 256, 0, stream>>>(Qg, Kz, Vz, Mg, Og);
    } else {
        fattn_fb<<<dim3(512), 256, 0, stream>>>(Qg, Kg, Vg, Mg, Og);
    }
}

// Round 9
// 432.955 us; speedup vs baseline: 1.7791x; 1.1116x over previous
//
#include <hip/hip_runtime.h>
#include <stdint.h>

// Fused attention: S=(x1@x2^T)*0.2; P=softmax(S); P=mask?P/0.9:0; O=P@x3
// B=16, SQ=SK=2048, D=DV=128. fp32 in/out, int32 mask, bf16 MFMA compute.
//
// R12 vs R11 (main 163us REGRESSION: unified VGPR+AGPR budget is 256/wave at
// 2 waves/SIMD; compiler split 128V+128A and my ~280-reg demand spilled 66MB):
//  K in registers WITHOUT ping-pong: kc[8] (32 regs, transient) loaded at
//  STEP top for the CURRENT tile. Kz is L2-resident (512KB/batch, XCD-pinned,
//  co-resident blocks share batch) -> ~200-400cy L2 hits; the ~40 instrs of
//  pack/stage/mask-issue between load and QK^T + compiler waits cover it.
//  No full-tile lookahead needed for L2 data. Ledger: aQ32 + o64(AGPR) +
//  kc32 + mld16(+16 trans) + s16 + temps ~= 200-230 <= 256 -> NO SPILL.
//  Still removes 8 bK ds_read_b128/wave/tile + K half of gload_lds staging:
//  LDS pipe ~2900 -> ~1800 cyc/tile/CU; K traffic moves to idle vmem/L2 path
//  (~5 TB/s demand vs 34.5 achievable). LDS 43KB (Vbuf dbuf 32K + Ps 10K).
//  Pre-commit: WRITE_SIZE clean but main >=118us => LDS-pipe theory false ->
//  next lever is co-resident-block phase stagger, not traffic.
//  Carried from R8 (124us main, best): 64q x 64k / 4 waves (32q x 32k); V in
//  dbuf LDS via gload_lds, ONE barrier/tile; in-loop nontemporal mask dwords
//  ping-ponged one tile ahead, bit-packed at consume; prep_k/prep_v passes;
//  XCD swizzle; exp2 static-max softmax; cvt_pk; setprio; cross-wk epilogue.
//  Fallback (ws < 16MB): R4 kernel.

#define B_   16
#define SQ_  2048
#define SK_  2048
#define D_   128
#define DV_  128
#define BK   64
#define NT   (SK_ / BK)   // 32 tiles

typedef short  s16x8 __attribute__((ext_vector_type(8)));   // MFMA A/B frag
typedef float  f32x4 __attribute__((ext_vector_type(4)));   // MFMA C/D frag
typedef unsigned int u32x4 __attribute__((ext_vector_type(4)));
typedef unsigned short u16;
typedef unsigned int   u32;

// f32 pair -> packed bf16x2, RNE, single instruction (no builtin on gfx950).
__device__ __forceinline__ u32 pk2(float a, float b) {
    u32 r;
    asm("v_cvt_pk_bf16_f32 %0, %1, %2" : "=v"(r) : "v"(a), "v"(b));
    return r;
}
__device__ __forceinline__ u16 f2bf(float f) { return (u16)pk2(f, 0.0f); }

// async global->LDS, 16B per lane. dst = wave-uniform base (HW adds lane*16).
__device__ __forceinline__ void gload16(void* lds, const void* g) {
    __builtin_amdgcn_global_load_lds((const __attribute__((address_space(1))) u32*)g,
                                     (__attribute__((address_space(3))) u32*)lds,
                                     16, 0, 0);
}

// ---------------- pre-pass: K -> bf16, bank-swizzled ----------------
// Kz[b][k][c] with c = col ^ ((k&7)<<3). 8 MB.
__global__ __launch_bounds__(256)
void prep_k(const float* __restrict__ Kg, u16* __restrict__ Kz)
{
    int g   = blockIdx.x * 256 + threadIdx.x;   // 524288 = 16*2048*16
    int b   = g >> 15;
    int rem = g & 32767;
    int k   = rem >> 4;
    int grp = rem & 15;
    const float* src = Kg + ((size_t)b * SK_ + k) * D_ + grp * 8;
    float4 x = *(const float4*)(src);
    float4 y = *(const float4*)(src + 4);
    u32x4 w = { pk2(x.x, x.y), pk2(x.z, x.w), pk2(y.x, y.y), pk2(y.z, y.w) };
    int c = (grp * 8) ^ ((k & 7) << 3);
    *(u32x4*)(&Kz[((size_t)b * SK_ + k) * D_ + c]) = w;
}

// ---------------- pre-pass: V -> transposed bf16 tiles, swizzled ----------------
// Vz[b][kt][dv][c] with c = k_local ^ ((dv&7)<<3); tile = 128x64 bf16 = 16KB.
__global__ __launch_bounds__(256)
void prep_v(const float* __restrict__ Vg, u16* __restrict__ Vz)
{
    int g  = blockIdx.x * 256 + threadIdx.x;    // 524288 = 16*32*8*128
    int dv = g & 127;
    int kg = (g >> 7) & 7;
    int kt = (g >> 10) & 31;
    int b  = g >> 15;
    const float* src = Vg + ((size_t)b * SK_ + kt * 64 + kg * 8) * DV_ + dv;
    float v[8];
    #pragma unroll
    for (int jj = 0; jj < 8; ++jj) v[jj] = src[(size_t)jj * DV_];
    u32x4 w = { pk2(v[0], v[1]), pk2(v[2], v[3]), pk2(v[4], v[5]), pk2(v[6], v[7]) };
    int c = (kg * 8) ^ ((dv & 7) << 3);
    *(u32x4*)(&Vz[(((size_t)b * 32 + kt) * 128 + dv) * 64 + c]) = w;
}

// ---------------- main kernel ----------------
// One tile step. CUR/NXT: V LDS buffers. K loaded per-tile into kc (L2-hot).
// exp(0.2*s - 12) == exp2(s*0.28853901 - 17.3123405)
#define STEP(IT, CUR, NXT)                                                    \
  {                                                                           \
    /* K frags for THIS tile -> regs (L2 hit ~200-400cy; covered below) */    \
    s16x8 kc[8];                                                              \
    _Pragma("unroll")                                                         \
    for (int t = 0; t < 2; ++t)                                               \
      _Pragma("unroll")                                                       \
      for (int kb = 0; kb < 4; ++kb)                                          \
        kc[t * 4 + kb] = *(const s16x8*)(                                     \
            &Kz[kvbase + (size_t)(IT) * 8192                                  \
                + (wk * 32 + t * 16 + n16) * 128                              \
                + ((kb * 32 + quad * 8) ^ kxor)]);                            \
    /* pack this tile's mask bits (loads were issued last tile) */            \
    u32 mcur = 0;                                                             \
    _Pragma("unroll")                                                         \
    for (int i = 0; i < 16; ++i)                                              \
      mcur |= (mld[i] != 0 ? 1u : 0u) << i;                                   \
    if ((IT) + 1 < NT) {                                                      \
      /* V staging for IT+1 (async -> LDS) */                                 \
      const u16* Vt = Vz + kvbase + (size_t)((IT) + 1) * 8192;                \
      _Pragma("unroll")                                                       \
      for (int i = 0; i < 4; ++i) {                                           \
        int c16 = (wave * 4 + i) * 512;                                       \
        gload16(&Vbuf[NXT][c16], &Vt[c16 + lane * 8]);                        \
      }                                                                       \
      /* mask regs for IT+1 (nontemporal: don't evict Kz/Vz from L2) */       \
      _Pragma("unroll")                                                       \
      for (int qs = 0; qs < 2; ++qs)                                          \
        _Pragma("unroll")                                                     \
        for (int t = 0; t < 2; ++t)                                           \
          _Pragma("unroll")                                                   \
          for (int r = 0; r < 4; ++r)                                         \
            mld[qs * 8 + t * 4 + r] = __builtin_nontemporal_load(             \
                &mbase[(size_t)(qs * 16 + r) * SK_ + ((IT) + 1) * 64 + t * 16]); \
    }                                                                         \
    f32x4 s[2][2];                                                            \
    _Pragma("unroll")                                                         \
    for (int qs = 0; qs < 2; ++qs)                                            \
      _Pragma("unroll")                                                       \
      for (int t = 0; t < 2; ++t) s[qs][t] = (f32x4){0.f, 0.f, 0.f, 0.f};     \
    __builtin_amdgcn_s_setprio(1);                                            \
    _Pragma("unroll")                                                         \
    for (int kb = 0; kb < 4; ++kb) {                                          \
      _Pragma("unroll")                                                       \
      for (int t = 0; t < 2; ++t) {                                           \
        _Pragma("unroll")                                                     \
        for (int qs = 0; qs < 2; ++qs)                                        \
          s[qs][t] = __builtin_amdgcn_mfma_f32_16x16x32_bf16(                 \
              aQ[qs][kb], kc[t * 4 + kb], s[qs][t], 0, 0, 0);                 \
      }                                                                       \
    }                                                                         \
    __builtin_amdgcn_s_setprio(0);                                            \
    _Pragma("unroll")                                                         \
    for (int qs = 0; qs < 2; ++qs)                                            \
      _Pragma("unroll")                                                       \
      for (int t = 0; t < 2; ++t)                                             \
        _Pragma("unroll")                                                     \
        for (int r = 0; r < 4; ++r) {                                         \
          float p = __builtin_amdgcn_exp2f(                                   \
              fmaf(s[qs][t][r], 0.28853901f, -17.3123405f));                  \
          l_part[qs][r] += p;                          /* UNmasked denom */   \
          float pv = ((mcur >> (qs * 8 + t * 4 + r)) & 1u) ? p : 0.f;         \
          Ps[wave * 1280 + (qs * 16 + quad * 4 + r) * 40 + t * 16 + n16] =    \
              f2bf(pv);                                                       \
        }                                                                     \
    s16x8 aP0 = *(const s16x8*)(&Ps[wave * 1280 + n16 * 40 + quad * 8]);      \
    s16x8 aP1 = *(const s16x8*)(&Ps[wave * 1280 + (16 + n16) * 40 + quad * 8]); \
    __builtin_amdgcn_s_setprio(1);                                            \
    _Pragma("unroll")                                                         \
    for (int nt = 0; nt < 8; ++nt) {                                          \
      s16x8 bV = *(const s16x8*)(&Vbuf[CUR][(nt * 16 + n16) * 64 + vcoff]);   \
      o[0][nt] = __builtin_amdgcn_mfma_f32_16x16x32_bf16(aP0, bV, o[0][nt], 0, 0, 0); \
      o[1][nt] = __builtin_amdgcn_mfma_f32_16x16x32_bf16(aP1, bV, o[1][nt], 0, 0, 0); \
    }                                                                         \
    __builtin_amdgcn_s_setprio(0);                                            \
    __syncthreads();   /* NXT V staged + visible */                           \
  }

__global__ __launch_bounds__(256, 2)
void fattn_main(const float* __restrict__ Qg, const u16* __restrict__ Kz,
                const u16* __restrict__ Vz, const int* __restrict__ Mg,
                float* __restrict__ Og)
{
    __shared__ __align__(16) u16 Vbuf[2][128 * 64];   // 32768 B (epilogue: oxch)
    __shared__ __align__(16) u16 Ps[4 * 32 * 40];     // 10240 B
    __shared__ float lxch[64];                        //   256 B
    // 43264 B total

    const int tid  = threadIdx.x;
    const int wave = tid >> 6;
    const int lane = tid & 63;
    const int n16  = lane & 15;
    const int quad = lane >> 4;
    const int wq   = wave & 1;    // q-half: rows wq*32 .. wq*32+31
    const int wk   = wave >> 1;   // k-half: cols wk*32 .. wk*32+31

    // XCD-chunked swizzle (bijective, 512 % 8 == 0)
    const int raw = blockIdx.x;
    const int xcd = raw & 7;
    const int j   = raw >> 3;            // 0..63
    const int b   = xcd * 2 + (j & 1);   // batch
    const int qt  = j >> 1;              // q-tile 0..31
    const int q0  = qt << 6;             // 64 q-rows per block

    const int kxor  = (n16 & 7) << 3;                 // swizzle XOR (u16 units)
    const int vcoff = (wk * 32 + quad * 8) ^ kxor;    // V-frag col offset

    // ---- Q fragments straight from global (one-time) ----
    s16x8 aQ[2][4];
    #pragma unroll
    for (int qs = 0; qs < 2; ++qs) {
        const float* qsrc = Qg + ((size_t)b * SQ_ + q0 + wq * 32 + qs * 16 + n16) * D_;
        #pragma unroll
        for (int kb = 0; kb < 4; ++kb) {
            float4 x = *(const float4*)(qsrc + kb * 32 + quad * 8);
            float4 y = *(const float4*)(qsrc + kb * 32 + quad * 8 + 4);
            u32x4 w = { pk2(x.x, x.y), pk2(x.z, x.w), pk2(y.x, y.y), pk2(y.z, y.w) };
            aQ[qs][kb] = __builtin_bit_cast(s16x8, w);
        }
    }

    f32x4 o[2][8];
    #pragma unroll
    for (int qs = 0; qs < 2; ++qs)
        #pragma unroll
        for (int i = 0; i < 8; ++i) o[qs][i] = (f32x4){0.f, 0.f, 0.f, 0.f};
    float l_part[2][4] = {{0.f, 0.f, 0.f, 0.f}, {0.f, 0.f, 0.f, 0.f}};

    const size_t kvbase = (size_t)b * 262144;   // per-batch slab (u16 elems)
    const int* mbase = Mg + ((size_t)(b * SQ_ + q0 + wq * 32 + quad * 4)) * SK_
                     + wk * 32 + n16;

    // ---- prologue: V tile 0 -> LDS, mask tile 0 -> regs ----
    {
        const u16* Vt = Vz + kvbase;
        #pragma unroll
        for (int i = 0; i < 4; ++i) {
            int c16 = (wave * 4 + i) * 512;
            gload16(&Vbuf[0][c16], &Vt[c16 + lane * 8]);
        }
    }
    int mld[16];
    #pragma unroll
    for (int qs = 0; qs < 2; ++qs)
        #pragma unroll
        for (int t = 0; t < 2; ++t)
            #pragma unroll
            for (int r = 0; r < 4; ++r)
                mld[qs * 8 + t * 4 + r] = __builtin_nontemporal_load(
                    &mbase[(size_t)(qs * 16 + r) * SK_ + t * 16]);

    __syncthreads();   // tile 0 V staged + visible

    for (int it = 0; it < NT; it += 2) {
        STEP(it,     0, 1)
        STEP(it + 1, 1, 0)
    }

    // ---- epilogue: reduce l across n16 lanes; combine wk halves ----
    float lr[2][4];
    #pragma unroll
    for (int qs = 0; qs < 2; ++qs)
        #pragma unroll
        for (int r = 0; r < 4; ++r) {
            float l = l_part[qs][r];
            #pragma unroll
            for (int off = 1; off < 16; off <<= 1) l += __shfl_xor(l, off);
            lr[qs][r] = l;
        }
    float* oxch = (float*)Vbuf;   // 64 x 128 f32 = 32768 B, exact fit
    if (wk == 1) {
        #pragma unroll
        for (int qs = 0; qs < 2; ++qs)
            #pragma unroll
            for (int r = 0; r < 4; ++r) {
                int row = wq * 32 + qs * 16 + quad * 4 + r;
                #pragma unroll
                for (int nt = 0; nt < 8; ++nt)
                    oxch[row * 128 + nt * 16 + n16] = o[qs][nt][r];
                if (n16 == 0) lxch[row] = lr[qs][r];
            }
    }
    __syncthreads();
    if (wk == 0) {
        const float ksc = 1.0f / 0.9f;
        #pragma unroll
        for (int qs = 0; qs < 2; ++qs)
            #pragma unroll
            for (int r = 0; r < 4; ++r) {
                int row = wq * 32 + qs * 16 + quad * 4 + r;
                float inv = ksc / (lr[qs][r] + lxch[row]);
                size_t ob = ((size_t)b * SQ_ + q0 + row) * (size_t)DV_;
                #pragma unroll
                for (int nt = 0; nt < 8; ++nt)
                    Og[ob + nt * 16 + n16] =
                        (o[qs][nt][r] + oxch[row * 128 + nt * 16 + n16]) * inv;
            }
    }
}

// ---------------- fallback (R4 kernel, used only if workspace too small) ----------------
#define BQ_FB 64
#define LDQ  136
#define LDK  136
#define LDVT 72
#define LDP  72

__global__ __launch_bounds__(256, 2)
void fattn_fb(const float* __restrict__ Qg, const float* __restrict__ Kg,
              const float* __restrict__ Vg, const int* __restrict__ Mg,
              float* __restrict__ Og)
{
    __shared__ u16 Qs[BQ_FB * LDQ];
    __shared__ u16 Ks[BK * LDK];
    __shared__ u16 Vt[DV_ * LDVT];
    __shared__ u16 Ps[4 * 16 * LDP];

    const int tid  = threadIdx.x;
    const int wave = tid >> 6;
    const int lane = tid & 63;
    const int n16  = lane & 15;
    const int quad = lane >> 4;

    const int raw = blockIdx.x;
    const int xcd = raw & 7;
    const int j   = raw >> 3;
    const int b   = xcd * 2 + (j & 1);
    const int q0  = (j >> 1) << 6;

    const int srow = tid >> 4;
    const int scol = (tid & 15) * 8;
    const int vrot = (tid & 7) * 8;

    {
        const float* src = Qg + ((size_t)b * SQ_ + q0) * D_;
        #pragma unroll
        for (int c = 0; c < 4; ++c) {
            int row = c * 16 + srow;
            float4 v0 = *(const float4*)(&src[row * D_ + scol]);
            float4 v1 = *(const float4*)(&src[row * D_ + scol + 4]);
            uint4 pk = { pk2(v0.x, v0.y), pk2(v0.z, v0.w),
                         pk2(v1.x, v1.y), pk2(v1.z, v1.w) };
            *(uint4*)(&Qs[row * LDQ + scol]) = pk;
        }
    }
    __syncthreads();

    s16x8 aQ[4];
    {
        const int qr = wave * 16 + n16;
        #pragma unroll
        for (int kb = 0; kb < 4; ++kb)
            aQ[kb] = *(const s16x8*)(&Qs[qr * LDQ + kb * 32 + quad * 8]);
    }

    f32x4 o[8];
    #pragma unroll
    for (int i = 0; i < 8; ++i) o[i] = (f32x4){0.f, 0.f, 0.f, 0.f};
    float l_part[4] = {0.f, 0.f, 0.f, 0.f};

    const size_t mask_qbase = ((size_t)b * SQ_ + q0 + wave * 16 + quad * 4) * (size_t)SK_;
    const float* baseK = Kg + ((size_t)b * SK_) * D_;
    const float* baseV = Vg + ((size_t)b * SK_) * DV_;

    float4 kf[8], vf[8];
    #pragma unroll
    for (int c = 0; c < 4; ++c) {
        int row = c * 16 + srow;
        kf[2*c]   = *(const float4*)(&baseK[row * D_ + scol]);
        kf[2*c+1] = *(const float4*)(&baseK[row * D_ + scol + 4]);
        vf[2*c]   = *(const float4*)(&baseV[row * DV_ + scol]);
        vf[2*c+1] = *(const float4*)(&baseV[row * DV_ + scol + 4]);
    }
    int mkc[4][4], mkn[4][4];
    #pragma unroll
    for (int t = 0; t < 4; ++t)
        #pragma unroll
        for (int r = 0; r < 4; ++r)
            mkc[t][r] = Mg[mask_qbase + (size_t)r * SK_ + (t * 16 + n16)];

    for (int it = 0; it < NT; ++it) {
        __syncthreads();
        #pragma unroll
        for (int c = 0; c < 4; ++c) {
            int row = c * 16 + srow;
            uint4 pk = { pk2(kf[2*c].x, kf[2*c].y),     pk2(kf[2*c].z, kf[2*c].w),
                         pk2(kf[2*c+1].x, kf[2*c+1].y), pk2(kf[2*c+1].z, kf[2*c+1].w) };
            *(uint4*)(&Ks[row * LDK + scol]) = pk;
        }
        #pragma unroll
        for (int c = 0; c < 4; ++c) {
            int k    = c * 16 + srow;
            int rcol = (k + vrot) & 63;
            int dv0  = scol;
            u32 r0 = pk2(vf[2*c].x,   vf[2*c].y);
            u32 r1 = pk2(vf[2*c].z,   vf[2*c].w);
            u32 r2 = pk2(vf[2*c+1].x, vf[2*c+1].y);
            u32 r3 = pk2(vf[2*c+1].z, vf[2*c+1].w);
            Vt[(dv0 + 0) * LDVT + rcol] = (u16)r0;
            Vt[(dv0 + 1) * LDVT + rcol] = (u16)(r0 >> 16);
            Vt[(dv0 + 2) * LDVT + rcol] = (u16)r1;
            Vt[(dv0 + 3) * LDVT + rcol] = (u16)(r1 >> 16);
            Vt[(dv0 + 4) * LDVT + rcol] = (u16)r2;
            Vt[(dv0 + 5) * LDVT + rcol] = (u16)(r2 >> 16);
            Vt[(dv0 + 6) * LDVT + rcol] = (u16)r3;
            Vt[(dv0 + 7) * LDVT + rcol] = (u16)(r3 >> 16);
        }
        if (it + 1 < NT) {
            const int k0n = (it + 1) * BK;
            #pragma unroll
            for (int c = 0; c < 4; ++c) {
                int row = k0n + c * 16 + srow;
                kf[2*c]   = *(const float4*)(&baseK[row * D_ + scol]);
                kf[2*c+1] = *(const float4*)(&baseK[row * D_ + scol + 4]);
                vf[2*c]   = *(const float4*)(&baseV[row * DV_ + scol]);
                vf[2*c+1] = *(const float4*)(&baseV[row * DV_ + scol + 4]);
            }
            #pragma unroll
            for (int t = 0; t < 4; ++t)
                #pragma unroll
                for (int r = 0; r < 4; ++r)
                    mkn[t][r] = Mg[mask_qbase + (size_t)r * SK_ + (k0n + t * 16 + n16)];
        }
        __syncthreads();

        f32x4 s[4];
        #pragma unroll
        for (int t = 0; t < 4; ++t) s[t] = (f32x4){0.f, 0.f, 0.f, 0.f};
        #pragma unroll
        for (int kb = 0; kb < 4; ++kb) {
            #pragma unroll
            for (int t = 0; t < 4; ++t) {
                s16x8 bK = *(const s16x8*)(&Ks[(t * 16 + n16) * LDK + kb * 32 + quad * 8]);
                s[t] = __builtin_amdgcn_mfma_f32_16x16x32_bf16(aQ[kb], bK, s[t], 0, 0, 0);
            }
        }
        #pragma unroll
        for (int t = 0; t < 4; ++t)
            #pragma unroll
            for (int r = 0; r < 4; ++r) {
                float p = __expf(fmaf(s[t][r], 0.2f, -12.0f));
                l_part[r] += p;
                float pv = mkc[t][r] ? p : 0.f;
                Ps[(wave * 16 + quad * 4 + r) * LDP + t * 16 + n16] = f2bf(pv);
            }
        #pragma unroll
        for (int kk = 0; kk < 2; ++kk) {
            s16x8 aP = *(const s16x8*)(&Ps[(wave * 16 + n16) * LDP + kk * 32 + quad * 8]);
            #pragma unroll
            for (int nt = 0; nt < 8; ++nt) {
                int dv   = nt * 16 + n16;
                int rcol = (kk * 32 + quad * 8 + 8 * ((dv >> 3) & 7)) & 63;
                s16x8 bV = *(const s16x8*)(&Vt[dv * LDVT + rcol]);
                o[nt] = __builtin_amdgcn_mfma_f32_16x16x32_bf16(aP, bV, o[nt], 0, 0, 0);
            }
        }
        #pragma unroll
        for (int t = 0; t < 4; ++t)
            #pragma unroll
            for (int r = 0; r < 4; ++r) mkc[t][r] = mkn[t][r];
    }

    const float keep_scale = 1.0f / 0.9f;
    #pragma unroll
    for (int r = 0; r < 4; ++r) {
        float l = l_part[r];
        #pragma unroll
        for (int off = 1; off < 16; off <<= 1)
            l += __shfl_xor(l, off);
        float inv_l = keep_scale / l;
        size_t obase = ((size_t)b * SQ_ + q0 + wave * 16 + quad * 4 + r) * DV_;
        #pragma unroll
        for (int nt = 0; nt < 8; ++nt)
            Og[obase + nt * 16 + n16] = o[nt][r] * inv_l;
    }
}

extern "C" void kernel_launch(void* const* d_in, const int* in_sizes, int n_in,
                              void* d_out, int out_size, void* d_ws, size_t ws_size,
                              hipStream_t stream) {
    const float* Qg = (const float*)d_in[0];
    const float* Kg = (const float*)d_in[1];
    const float* Vg = (const float*)d_in[2];
    const int*   Mg = (const int*)d_in[3];
    float* Og = (float*)d_out;
    if (d_ws != nullptr && ws_size >= (size_t)16 * 1024 * 1024) {
        u16* Kz = (u16*)d_ws;                   // 8 MB swizzled bf16 K
        u16* Vz = Kz + 4194304;                 // 8 MB transposed+swizzled bf16 V
        prep_k<<<dim3(2048), 256, 0, stream>>>(Kg, Kz);
        prep_v<<<dim3(2048), 256, 0, stream>>>(Vg, Vz);
        fattn_main<<<dim3(512), 256, 0, stream>>>(Qg, Kz, Vz, Mg, Og);
    } else {
        fattn_fb<<<dim3(512), 256, 0, stream>>>(Qg, Kg, Vg, Mg, Og);
    }
}